// Round 4
// baseline (892.443 us; speedup 1.0000x reference)
//
#include <hip/hip_runtime.h>
#include <stdint.h>

#define D_FEAT 128
#define TOPK   128
#define KSPLIT 384            // 3 x 128 (h|h|l) . (h|l|h)
#define SCALE  4096.0f
#define SCALE2 16777216.0f    // SCALE^2 (2^24, exact)

typedef float    f32x4 __attribute__((ext_vector_type(4)));
typedef _Float16 half8 __attribute__((ext_vector_type(8)));

// ---------------- squared norms (unscaled f32) ----------------
__global__ __launch_bounds__(256) void sqnorm_kernel(const float* __restrict__ X,
                                                     float* __restrict__ out, int rows) {
    int r = blockIdx.x * 256 + threadIdx.x;
    if (r >= rows) return;
    const float4* p = (const float4*)(X + (size_t)r * D_FEAT);
    float s = 0.f;
    #pragma unroll
    for (int i = 0; i < D_FEAT / 4; ++i) {
        float4 v = p[i];
        s += v.x * v.x + v.y * v.y + v.z * v.z + v.w * v.w;
    }
    out[r] = s;
}

// ---------------- f32 -> scaled f16 (hi,lo) split, K-concatenated ----------------
__global__ __launch_bounds__(128) void split_kernel(const float* __restrict__ X,
                                                    unsigned short* __restrict__ out,
                                                    int isA) {
    int row = blockIdx.x;
    int k   = threadIdx.x;
    float a = X[(size_t)row * D_FEAT + k] * SCALE;
    _Float16 h = (_Float16)a;
    float hf = (float)h;
    _Float16 l = (_Float16)(a - hf);
    unsigned short hu, lu;
    __builtin_memcpy(&hu, &h, 2);
    __builtin_memcpy(&lu, &l, 2);
    size_t b = (size_t)row * KSPLIT;
    out[b + k]              = hu;
    out[b + D_FEAT + k]     = isA ? hu : lu;
    out[b + 2 * D_FEAT + k] = isA ? lu : hu;
}

// ---------------- MFMA distance kernel -> 16-bit keys ----------------
#define BM 128
#define BN 128
#define BKS 64
#define NSLAB (KSPLIT / BKS)   // 6
#define KTS 136                // key-tile LDS stride in u16 (272B, 16B-mult, bank-spread)

static __device__ __forceinline__ half8 lds_read_half8(const unsigned short* p) {
    half8 r;
    __builtin_memcpy(&r, p, 16);
    return r;
}

__global__ __launch_bounds__(256) void dist_mfma_kernel(
        const unsigned short* __restrict__ Asp,   // [n][384]
        const unsigned short* __restrict__ Bsp,   // [N][384]
        const float* __restrict__ x2,
        const float* __restrict__ y2,
        unsigned short* __restrict__ keyout,      // [chunk][N]
        int q0, int N, int rowsM) {
    // union: A/B staging (32 KB) and key tile (34 KB)
    __shared__ __align__(16) unsigned char shraw[BM * KTS * 2];  // 34816 B
    unsigned short* sh  = (unsigned short*)shraw;
    unsigned short* Ash = sh;
    unsigned short* Bsh = sh + BM * BKS;

    // XCD-aware swizzle: column-major per XCD (each XCD sees a contiguous N-band)
    const int nwg = (N / BN) * rowsM;      // multiple of 8 (N/BN = 512)
    const int cpx = nwg >> 3;
    const int bid = blockIdx.x;
    const int swz = (bid & 7) * cpx + (bid >> 3);
    const int col   = swz / rowsM;
    const int mrowi = swz - col * rowsM;
    const int nb = col * BN;
    const int mb = mrowi * BM;

    const int tid  = threadIdx.x;
    const int lane = tid & 63;
    const int wid  = tid >> 6;
    const int wr   = wid >> 1, wc = wid & 1;

    const int srow = tid >> 3;            // 0..31
    const int sc   = tid & 7;             // 16B chunk col 0..7

    f32x4 acc[4][4];
    #pragma unroll
    for (int i = 0; i < 4; ++i)
        #pragma unroll
        for (int j = 0; j < 4; ++j)
            acc[i][j] = (f32x4){0.f, 0.f, 0.f, 0.f};

    uint4 ra[4], rb[4];
    #pragma unroll
    for (int it = 0; it < 4; ++it) {
        int row = it * 32 + srow;
        ra[it] = *(const uint4*)(Asp + (size_t)(q0 + mb + row) * KSPLIT + sc * 8);
        rb[it] = *(const uint4*)(Bsp + (size_t)(nb + row)      * KSPLIT + sc * 8);
    }

    for (int s = 0; s < NSLAB; ++s) {
        __syncthreads();
        #pragma unroll
        for (int it = 0; it < 4; ++it) {
            int row = it * 32 + srow;
            int dst = row * 8 + (sc ^ (row & 7));
            *(uint4*)(Ash + dst * 8) = ra[it];
            *(uint4*)(Bsh + dst * 8) = rb[it];
        }
        if (s + 1 < NSLAB) {
            int kt = (s + 1) * BKS;
            #pragma unroll
            for (int it = 0; it < 4; ++it) {
                int row = it * 32 + srow;
                ra[it] = *(const uint4*)(Asp + (size_t)(q0 + mb + row) * KSPLIT + kt + sc * 8);
                rb[it] = *(const uint4*)(Bsp + (size_t)(nb + row)      * KSPLIT + kt + sc * 8);
            }
        }
        __syncthreads();
        #pragma unroll
        for (int kk = 0; kk < 2; ++kk) {
            half8 af[4], bf[4];
            #pragma unroll
            for (int f = 0; f < 4; ++f) {
                int m = wr * 64 + f * 16 + (lane & 15);
                int c = kk * 4 + (lane >> 4);
                af[f] = lds_read_half8(Ash + (m * 8 + (c ^ (m & 7))) * 8);
                int nn = wc * 64 + f * 16 + (lane & 15);
                bf[f] = lds_read_half8(Bsh + (nn * 8 + (c ^ (nn & 7))) * 8);
            }
            #pragma unroll
            for (int i = 0; i < 4; ++i)
                #pragma unroll
                for (int j = 0; j < 4; ++j)
                    acc[i][j] = __builtin_amdgcn_mfma_f32_16x16x32_f16(af[i], bf[j], acc[i][j], 0, 0, 0);
        }
    }

    // ---- epilogue: keys -> LDS tile -> coalesced uint4 stores ----
    __syncthreads();                       // all waves done reading A/B LDS
    unsigned short* ktile = sh;            // reuse (34816 B = 128 x KTS u16)

    float x2v[16];
    #pragma unroll
    for (int fi = 0; fi < 4; ++fi)
        #pragma unroll
        for (int r = 0; r < 4; ++r)
            x2v[fi * 4 + r] = x2[q0 + mb + wr * 64 + fi * 16 + (lane >> 4) * 4 + r];
    #pragma unroll
    for (int fj = 0; fj < 4; ++fj) {
        float yv = y2[nb + wc * 64 + fj * 16 + (lane & 15)];
        #pragma unroll
        for (int fi = 0; fi < 4; ++fi) {
            #pragma unroll
            for (int r = 0; r < 4; ++r) {
                float d = fmaf(-2.0f, acc[fi][fj][r], SCALE2 * (x2v[fi * 4 + r] + yv));
                d = fmaxf(d, 0.0f);
                int ml = wr * 64 + fi * 16 + (lane >> 4) * 4 + r;
                int nl = wc * 64 + fj * 16 + (lane & 15);
                ktile[ml * KTS + nl] = (unsigned short)(__float_as_uint(d) >> 15);
            }
        }
    }
    __syncthreads();
    #pragma unroll
    for (int it = 0; it < 8; ++it) {
        int idx = it * 256 + tid;          // 0..2047
        int row = idx >> 4;                // 0..127
        int ch  = idx & 15;                // 0..15 (16B chunks)
        uint4 v = *(const uint4*)(ktile + row * KTS + ch * 8);
        *(uint4*)(keyout + (size_t)(mb + row) * N + nb + ch * 8) = v;
    }
}

// ---------------- selection + vote on 16-bit keys (v4: 3-probe x 8-pass) ----------------
#define SEL_T 1024
#define NPK   32
#define CAP   2048

__global__ __launch_bounds__(SEL_T, 4) void select4_kernel(
        const unsigned short* __restrict__ keys,
        const float* __restrict__ labels,
        const float* __restrict__ Q, const float* __restrict__ Dta,
        int* __restrict__ out, int q0, int N, int n_total, int out_size) {
    const int tid = threadIdx.x;
    const unsigned short* row = keys + (size_t)blockIdx.x * N;
    const int qi = q0 + blockIdx.x;

    uint32_t pk[NPK];
    #pragma unroll
    for (int i = 0; i < 8; ++i) {
        uint4 v = *(const uint4*)(row + i * 8192 + tid * 8);
        pk[i * 4 + 0] = v.x; pk[i * 4 + 1] = v.y;
        pk[i * 4 + 2] = v.z; pk[i * 4 + 3] = v.w;
    }
    // pk[r] halves cover j = (r>>2)*8192 + tid*8 + (r&3)*2 + h

    __shared__ unsigned int red[2][3][16];
    __shared__ unsigned int tot[2][3];
    __shared__ unsigned int mcnt, votes_sh;
    __shared__ double       cval[CAP];
    __shared__ unsigned int ckey[CAP];

    if (tid == 0) { mcnt = 0; votes_sh = 0; }

    // 8 passes x 3 probes: resolve 16-bit tau (smallest t with count(key<t) >= TOPK)
    uint32_t lo = 0, hi = 65536, base = 0;
    #pragma unroll
    for (int pass = 0; pass < 8; ++pass) {
        uint32_t qs = (hi - lo) >> 2;
        uint32_t p1 = lo + qs, p2 = p1 + qs, p3 = p2 + qs;
        uint32_t c1 = 0, c2 = 0, c3 = 0;
        #pragma unroll
        for (int r2 = 0; r2 < NPK; ++r2) {
            uint32_t p = pk[r2];
            uint32_t a = p & 0xFFFFu, b = p >> 16;
            c1 += (a < p1) + (b < p1);
            c2 += (a < p2) + (b < p2);
            c3 += (a < p3) + (b < p3);
        }
        #pragma unroll
        for (int off = 32; off > 0; off >>= 1) {
            c1 += __shfl_down(c1, off, 64);
            c2 += __shfl_down(c2, off, 64);
            c3 += __shfl_down(c3, off, 64);
        }
        int bsel = pass & 1;
        if ((tid & 63) == 0) {
            int w = tid >> 6;
            red[bsel][0][w] = c1; red[bsel][1][w] = c2; red[bsel][2][w] = c3;
        }
        __syncthreads();
        if (tid < 48) {
            int g = tid >> 4, i = tid & 15;
            unsigned int v = red[bsel][g][i];
            v += __shfl_xor(v, 1, 64);
            v += __shfl_xor(v, 2, 64);
            v += __shfl_xor(v, 4, 64);
            v += __shfl_xor(v, 8, 64);
            if (i == 0) tot[bsel][g] = v;
        }
        __syncthreads();
        uint32_t t1 = tot[bsel][0], t2 = tot[bsel][1], t3 = tot[bsel][2];
        if      (t1 >= TOPK) { hi = p1; }
        else if (t2 >= TOPK) { lo = p1; hi = p2; base = t1; }
        else if (t3 >= TOPK) { lo = p2; hi = p3; base = t2; }
        else                 { lo = p3;          base = t3; }
    }
    const uint32_t tau    = lo;
    const uint32_t t_take = TOPK - base;

    // ---- vote below tau; gather tau-ties with exact f64 distances ----
    uint32_t votes = 0;
    #pragma unroll
    for (int r2 = 0; r2 < NPK; ++r2) {
        uint32_t p = pk[r2];
        #pragma unroll
        for (int h = 0; h < 2; ++h) {
            uint32_t key = (h == 0) ? (p & 0xFFFFu) : (p >> 16);
            if (key <= tau) {
                int j = (r2 >> 2) * 8192 + tid * 8 + (r2 & 3) * 2 + h;
                if (key < tau) {
                    votes += (labels[j] > 0.5f) ? 1u : 0u;
                } else {
                    unsigned int lab = (labels[j] > 0.5f) ? 0x80000000u : 0u;
                    unsigned int e = atomicAdd(&mcnt, 1u);
                    if (e < CAP) {
                        const float* qp = Q   + (size_t)qi * D_FEAT;
                        const float* dp = Dta + (size_t)j  * D_FEAT;
                        double sacc = 0.0;
                        for (int k = 0; k < D_FEAT; ++k) {
                            double df = (double)qp[k] - (double)dp[k];
                            sacc = fma(df, df, sacc);
                        }
                        cval[e] = sacc;
                        ckey[e] = (unsigned int)j | lab;
                    }
                }
            }
        }
    }
    #pragma unroll
    for (int off = 32; off > 0; off >>= 1)
        votes += __shfl_down(votes, off, 64);
    if ((tid & 63) == 0 && votes) atomicAdd(&votes_sh, votes);
    __syncthreads();

    unsigned int m = mcnt; if (m > CAP) m = CAP;
    for (unsigned int e = tid; e < m; e += SEL_T) {
        double       ve = cval[e];
        unsigned int ke = ckey[e];
        unsigned int ie = ke & 0x7FFFFFFFu;
        unsigned int rank = 0;
        for (unsigned int f = 0; f < m; ++f) {
            double       vf = cval[f];
            unsigned int jf = ckey[f] & 0x7FFFFFFFu;
            rank += (vf < ve || (vf == ve && jf < ie)) ? 1u : 0u;
        }
        if (rank < t_take && (ke & 0x80000000u)) atomicAdd(&votes_sh, 1u);
    }
    __syncthreads();

    if (tid == 0) {
        unsigned int v1 = votes_sh;
        out[qi] = (v1 > TOPK / 2) ? 1 : 0;          // 64/64 tie -> class 0
        if (qi == 0 && out_size > n_total) out[n_total] = 0;
    }
}

// ---------------- host ----------------
extern "C" void kernel_launch(void* const* d_in, const int* in_sizes, int n_in,
                              void* d_out, int out_size, void* d_ws, size_t ws_size,
                              hipStream_t stream) {
    const float* Q   = (const float*)d_in[0];
    const float* Dta = (const float*)d_in[1];
    const float* L   = (const float*)d_in[2];
    const int n = in_sizes[0] / D_FEAT;    // 2048
    const int N = in_sizes[1] / D_FEAT;    // 65536
    int* out = (int*)d_out;

    char* ws = (char*)d_ws;
    size_t off = 0;
    float* y2 = (float*)(ws + off); off += (((size_t)N * 4) + 255) & ~(size_t)255;
    float* x2 = (float*)(ws + off); off += (((size_t)n * 4) + 255) & ~(size_t)255;
    unsigned short* Asp = (unsigned short*)(ws + off); off += (((size_t)n * KSPLIT * 2) + 255) & ~(size_t)255;
    unsigned short* Bsp = (unsigned short*)(ws + off); off += (((size_t)N * KSPLIT * 2) + 255) & ~(size_t)255;
    unsigned short* keybuf = (unsigned short*)(ws + off);
    size_t avail = (ws_size > off) ? (ws_size - off) : 0;

    long maxQ = (long)(avail / ((size_t)N * 2));
    int chunkQ;
    if (maxQ >= n) chunkQ = n;
    else { chunkQ = (int)((maxQ / BM) * BM); if (chunkQ < BM) chunkQ = BM; }

    sqnorm_kernel<<<dim3((N + 255) / 256), dim3(256), 0, stream>>>(Dta, y2, N);
    sqnorm_kernel<<<dim3((n + 255) / 256), dim3(256), 0, stream>>>(Q, x2, n);
    split_kernel<<<dim3(n), dim3(128), 0, stream>>>(Q, Asp, 1);
    split_kernel<<<dim3(N), dim3(128), 0, stream>>>(Dta, Bsp, 0);

    for (int q0 = 0; q0 < n; q0 += chunkQ) {
        int q = n - q0; if (q > chunkQ) q = chunkQ;
        int rowsM = q / BM;
        int nwg = (N / BN) * rowsM;
        dist_mfma_kernel<<<dim3(nwg), dim3(256), 0, stream>>>(Asp, Bsp, x2, y2, keybuf, q0, N, rowsM);
        select4_kernel<<<dim3(q), dim3(SEL_T), 0, stream>>>(keybuf, L, Q, Dta, out, q0, N, n, out_size);
    }
}

// Round 5
// 878.946 us; speedup vs baseline: 1.0154x; 1.0154x over previous
//
#include <hip/hip_runtime.h>
#include <stdint.h>

#define D_FEAT 128
#define TOPK   128
#define KSPLIT 384            // 3 x 128 (h|h|l) . (h|l|h)
#define SCALE  4096.0f
#define SCALE2 16777216.0f    // SCALE^2 (2^24, exact)

typedef float    f32x4 __attribute__((ext_vector_type(4)));
typedef _Float16 half8 __attribute__((ext_vector_type(8)));

// ---------------- squared norms (unscaled f32) ----------------
__global__ __launch_bounds__(256) void sqnorm_kernel(const float* __restrict__ X,
                                                     float* __restrict__ out, int rows) {
    int r = blockIdx.x * 256 + threadIdx.x;
    if (r >= rows) return;
    const float4* p = (const float4*)(X + (size_t)r * D_FEAT);
    float s = 0.f;
    #pragma unroll
    for (int i = 0; i < D_FEAT / 4; ++i) {
        float4 v = p[i];
        s += v.x * v.x + v.y * v.y + v.z * v.z + v.w * v.w;
    }
    out[r] = s;
}

// ---------------- f32 -> scaled f16 (hi,lo) split, K-concatenated ----------------
__global__ __launch_bounds__(128) void split_kernel(const float* __restrict__ X,
                                                    unsigned short* __restrict__ out,
                                                    int isA) {
    int row = blockIdx.x;
    int k   = threadIdx.x;
    float a = X[(size_t)row * D_FEAT + k] * SCALE;
    _Float16 h = (_Float16)a;
    float hf = (float)h;
    _Float16 l = (_Float16)(a - hf);
    unsigned short hu, lu;
    __builtin_memcpy(&hu, &h, 2);
    __builtin_memcpy(&lu, &l, 2);
    size_t b = (size_t)row * KSPLIT;
    out[b + k]              = hu;
    out[b + D_FEAT + k]     = isA ? hu : lu;
    out[b + 2 * D_FEAT + k] = isA ? lu : hu;
}

// ---------------- MFMA distance kernel -> 16-bit keys (tile-major output) ----------------
#define BM 128
#define BN 128
#define BKS 64
#define NSLAB (KSPLIT / BKS)   // 6
#define KTS 136                // key-tile LDS stride in u16
#define TILE_ELEMS (BM * BN)   // 16384 u16 = 32 KB per tile

static __device__ __forceinline__ half8 lds_read_half8(const unsigned short* p) {
    half8 r;
    __builtin_memcpy(&r, p, 16);
    return r;
}

__global__ __launch_bounds__(256) void dist_mfma_kernel(
        const unsigned short* __restrict__ Asp,   // [n][384]
        const unsigned short* __restrict__ Bsp,   // [N][384]
        const float* __restrict__ x2,
        const float* __restrict__ y2,
        unsigned short* __restrict__ keyout,      // tile-major [mtile][ntile][128*128]
        int q0, int N, int rowsM) {
    __shared__ __align__(16) unsigned char shraw[BM * KTS * 2];  // 34816 B
    unsigned short* sh  = (unsigned short*)shraw;
    unsigned short* Ash = sh;
    unsigned short* Bsh = sh + BM * BKS;

    // XCD-aware swizzle: column-major per XCD (contiguous N-band per XCD)
    const int nwg = (N / BN) * rowsM;
    const int cpx = nwg >> 3;
    const int bid = blockIdx.x;
    const int swz = (bid & 7) * cpx + (bid >> 3);
    const int col   = swz / rowsM;
    const int mrowi = swz - col * rowsM;
    const int nb = col * BN;
    const int mb = mrowi * BM;

    const int tid  = threadIdx.x;
    const int lane = tid & 63;
    const int wid  = tid >> 6;
    const int wr   = wid >> 1, wc = wid & 1;

    const int srow = tid >> 3;            // 0..31
    const int sc   = tid & 7;             // 16B chunk col 0..7

    f32x4 acc[4][4];
    #pragma unroll
    for (int i = 0; i < 4; ++i)
        #pragma unroll
        for (int j = 0; j < 4; ++j)
            acc[i][j] = (f32x4){0.f, 0.f, 0.f, 0.f};

    uint4 ra[4], rb[4];
    #pragma unroll
    for (int it = 0; it < 4; ++it) {
        int row = it * 32 + srow;
        ra[it] = *(const uint4*)(Asp + (size_t)(q0 + mb + row) * KSPLIT + sc * 8);
        rb[it] = *(const uint4*)(Bsp + (size_t)(nb + row)      * KSPLIT + sc * 8);
    }

    for (int s = 0; s < NSLAB; ++s) {
        __syncthreads();
        #pragma unroll
        for (int it = 0; it < 4; ++it) {
            int row = it * 32 + srow;
            int dst = row * 8 + (sc ^ (row & 7));
            *(uint4*)(Ash + dst * 8) = ra[it];
            *(uint4*)(Bsh + dst * 8) = rb[it];
        }
        if (s + 1 < NSLAB) {
            int kt = (s + 1) * BKS;
            #pragma unroll
            for (int it = 0; it < 4; ++it) {
                int row = it * 32 + srow;
                ra[it] = *(const uint4*)(Asp + (size_t)(q0 + mb + row) * KSPLIT + kt + sc * 8);
                rb[it] = *(const uint4*)(Bsp + (size_t)(nb + row)      * KSPLIT + kt + sc * 8);
            }
        }
        __syncthreads();
        #pragma unroll
        for (int kk = 0; kk < 2; ++kk) {
            half8 af[4], bf[4];
            #pragma unroll
            for (int f = 0; f < 4; ++f) {
                int m = wr * 64 + f * 16 + (lane & 15);
                int c = kk * 4 + (lane >> 4);
                af[f] = lds_read_half8(Ash + (m * 8 + (c ^ (m & 7))) * 8);
                int nn = wc * 64 + f * 16 + (lane & 15);
                bf[f] = lds_read_half8(Bsh + (nn * 8 + (c ^ (nn & 7))) * 8);
            }
            #pragma unroll
            for (int i = 0; i < 4; ++i)
                #pragma unroll
                for (int j = 0; j < 4; ++j)
                    acc[i][j] = __builtin_amdgcn_mfma_f32_16x16x32_f16(af[i], bf[j], acc[i][j], 0, 0, 0);
        }
    }

    // ---- epilogue: keys -> LDS tile -> one contiguous 32 KB blob per block ----
    __syncthreads();
    unsigned short* ktile = sh;

    float x2v[16];
    #pragma unroll
    for (int fi = 0; fi < 4; ++fi)
        #pragma unroll
        for (int r = 0; r < 4; ++r)
            x2v[fi * 4 + r] = x2[q0 + mb + wr * 64 + fi * 16 + (lane >> 4) * 4 + r];
    #pragma unroll
    for (int fj = 0; fj < 4; ++fj) {
        float yv = y2[nb + wc * 64 + fj * 16 + (lane & 15)];
        #pragma unroll
        for (int fi = 0; fi < 4; ++fi) {
            #pragma unroll
            for (int r = 0; r < 4; ++r) {
                float d = fmaf(-2.0f, acc[fi][fj][r], SCALE2 * (x2v[fi * 4 + r] + yv));
                d = fmaxf(d, 0.0f);
                int ml = wr * 64 + fi * 16 + (lane >> 4) * 4 + r;
                int nl = wc * 64 + fj * 16 + (lane & 15);
                ktile[ml * KTS + nl] = (unsigned short)(__float_as_uint(d) >> 15);
            }
        }
    }
    __syncthreads();
    const size_t tilebase = ((size_t)mrowi * (N / BN) + col) * TILE_ELEMS;
    #pragma unroll
    for (int it = 0; it < 8; ++it) {
        int idx = it * 256 + tid;          // 0..2047
        int row = idx >> 4;                // 0..127
        int ch  = idx & 15;                // 16B chunks
        uint4 v = *(const uint4*)(ktile + row * KTS + ch * 8);
        *(uint4*)(keyout + tilebase + row * BN + ch * 8) = v;   // contiguous 32 KB/block
    }
}

// ---------------- selection + vote on 16-bit keys (tile-major input) ----------------
#define SEL_T 1024
#define NPK   32
#define CAP   2048

__global__ __launch_bounds__(SEL_T, 4) void select4_kernel(
        const unsigned short* __restrict__ keys,
        const float* __restrict__ labels,
        const float* __restrict__ Q, const float* __restrict__ Dta,
        int* __restrict__ out, int q0, int N, int n_total, int out_size) {
    const int tid = threadIdx.x;
    const int qi  = q0 + blockIdx.x;
    const int tr  = blockIdx.x >> 7;       // m-tile index
    const int rin = blockIdx.x & 127;      // row within tile
    const unsigned short* rowbase = keys + ((size_t)tr * (N / BN)) * TILE_ELEMS + rin * BN;

    uint32_t pk[NPK];
    #pragma unroll
    for (int i = 0; i < 8; ++i) {
        int g = i * 8192 + tid * 8;        // global column of first element
        const unsigned short* p = rowbase + (size_t)(g >> 7) * TILE_ELEMS + (g & 127);
        uint4 v = *(const uint4*)p;
        pk[i * 4 + 0] = v.x; pk[i * 4 + 1] = v.y;
        pk[i * 4 + 2] = v.z; pk[i * 4 + 3] = v.w;
    }
    // pk[r] halves cover j = (r>>2)*8192 + tid*8 + (r&3)*2 + h  (global column, unchanged)

    __shared__ unsigned int red[2][3][16];
    __shared__ unsigned int tot[2][3];
    __shared__ unsigned int mcnt, votes_sh;
    __shared__ double       cval[CAP];
    __shared__ unsigned int ckey[CAP];

    if (tid == 0) { mcnt = 0; votes_sh = 0; }

    // 8 passes x 3 probes: resolve 16-bit tau
    uint32_t lo = 0, hi = 65536, base = 0;
    #pragma unroll
    for (int pass = 0; pass < 8; ++pass) {
        uint32_t qs = (hi - lo) >> 2;
        uint32_t p1 = lo + qs, p2 = p1 + qs, p3 = p2 + qs;
        uint32_t c1 = 0, c2 = 0, c3 = 0;
        #pragma unroll
        for (int r2 = 0; r2 < NPK; ++r2) {
            uint32_t p = pk[r2];
            uint32_t a = p & 0xFFFFu, b = p >> 16;
            c1 += (a < p1) + (b < p1);
            c2 += (a < p2) + (b < p2);
            c3 += (a < p3) + (b < p3);
        }
        #pragma unroll
        for (int off = 32; off > 0; off >>= 1) {
            c1 += __shfl_down(c1, off, 64);
            c2 += __shfl_down(c2, off, 64);
            c3 += __shfl_down(c3, off, 64);
        }
        int bsel = pass & 1;
        if ((tid & 63) == 0) {
            int w = tid >> 6;
            red[bsel][0][w] = c1; red[bsel][1][w] = c2; red[bsel][2][w] = c3;
        }
        __syncthreads();
        if (tid < 48) {
            int g = tid >> 4, i = tid & 15;
            unsigned int v = red[bsel][g][i];
            v += __shfl_xor(v, 1, 64);
            v += __shfl_xor(v, 2, 64);
            v += __shfl_xor(v, 4, 64);
            v += __shfl_xor(v, 8, 64);
            if (i == 0) tot[bsel][g] = v;
        }
        __syncthreads();
        uint32_t t1 = tot[bsel][0], t2 = tot[bsel][1], t3 = tot[bsel][2];
        if      (t1 >= TOPK) { hi = p1; }
        else if (t2 >= TOPK) { lo = p1; hi = p2; base = t1; }
        else if (t3 >= TOPK) { lo = p2; hi = p3; base = t2; }
        else                 { lo = p3;          base = t3; }
    }
    const uint32_t tau    = lo;
    const uint32_t t_take = TOPK - base;

    // ---- vote below tau; gather tau-ties with exact f64 distances ----
    uint32_t votes = 0;
    #pragma unroll
    for (int r2 = 0; r2 < NPK; ++r2) {
        uint32_t p = pk[r2];
        #pragma unroll
        for (int h = 0; h < 2; ++h) {
            uint32_t key = (h == 0) ? (p & 0xFFFFu) : (p >> 16);
            if (key <= tau) {
                int j = (r2 >> 2) * 8192 + tid * 8 + (r2 & 3) * 2 + h;
                if (key < tau) {
                    votes += (labels[j] > 0.5f) ? 1u : 0u;
                } else {
                    unsigned int lab = (labels[j] > 0.5f) ? 0x80000000u : 0u;
                    unsigned int e = atomicAdd(&mcnt, 1u);
                    if (e < CAP) {
                        const float* qp = Q   + (size_t)qi * D_FEAT;
                        const float* dp = Dta + (size_t)j  * D_FEAT;
                        double sacc = 0.0;
                        for (int k = 0; k < D_FEAT; ++k) {
                            double df = (double)qp[k] - (double)dp[k];
                            sacc = fma(df, df, sacc);
                        }
                        cval[e] = sacc;
                        ckey[e] = (unsigned int)j | lab;
                    }
                }
            }
        }
    }
    #pragma unroll
    for (int off = 32; off > 0; off >>= 1)
        votes += __shfl_down(votes, off, 64);
    if ((tid & 63) == 0 && votes) atomicAdd(&votes_sh, votes);
    __syncthreads();

    unsigned int m = mcnt; if (m > CAP) m = CAP;
    for (unsigned int e = tid; e < m; e += SEL_T) {
        double       ve = cval[e];
        unsigned int ke = ckey[e];
        unsigned int ie = ke & 0x7FFFFFFFu;
        unsigned int rank = 0;
        for (unsigned int f = 0; f < m; ++f) {
            double       vf = cval[f];
            unsigned int jf = ckey[f] & 0x7FFFFFFFu;
            rank += (vf < ve || (vf == ve && jf < ie)) ? 1u : 0u;
        }
        if (rank < t_take && (ke & 0x80000000u)) atomicAdd(&votes_sh, 1u);
    }
    __syncthreads();

    if (tid == 0) {
        unsigned int v1 = votes_sh;
        out[qi] = (v1 > TOPK / 2) ? 1 : 0;          // 64/64 tie -> class 0
        if (qi == 0 && out_size > n_total) out[n_total] = 0;
    }
}

// ---------------- host ----------------
extern "C" void kernel_launch(void* const* d_in, const int* in_sizes, int n_in,
                              void* d_out, int out_size, void* d_ws, size_t ws_size,
                              hipStream_t stream) {
    const float* Q   = (const float*)d_in[0];
    const float* Dta = (const float*)d_in[1];
    const float* L   = (const float*)d_in[2];
    const int n = in_sizes[0] / D_FEAT;    // 2048
    const int N = in_sizes[1] / D_FEAT;    // 65536
    int* out = (int*)d_out;

    char* ws = (char*)d_ws;
    size_t off = 0;
    float* y2 = (float*)(ws + off); off += (((size_t)N * 4) + 255) & ~(size_t)255;
    float* x2 = (float*)(ws + off); off += (((size_t)n * 4) + 255) & ~(size_t)255;
    unsigned short* Asp = (unsigned short*)(ws + off); off += (((size_t)n * KSPLIT * 2) + 255) & ~(size_t)255;
    unsigned short* Bsp = (unsigned short*)(ws + off); off += (((size_t)N * KSPLIT * 2) + 255) & ~(size_t)255;
    unsigned short* keybuf = (unsigned short*)(ws + off);
    size_t avail = (ws_size > off) ? (ws_size - off) : 0;

    long maxQ = (long)(avail / ((size_t)N * 2));
    int chunkQ;
    if (maxQ >= n) chunkQ = n;
    else { chunkQ = (int)((maxQ / BM) * BM); if (chunkQ < BM) chunkQ = BM; }

    sqnorm_kernel<<<dim3((N + 255) / 256), dim3(256), 0, stream>>>(Dta, y2, N);
    sqnorm_kernel<<<dim3((n + 255) / 256), dim3(256), 0, stream>>>(Q, x2, n);
    split_kernel<<<dim3(n), dim3(128), 0, stream>>>(Q, Asp, 1);
    split_kernel<<<dim3(N), dim3(128), 0, stream>>>(Dta, Bsp, 0);

    for (int q0 = 0; q0 < n; q0 += chunkQ) {
        int q = n - q0; if (q > chunkQ) q = chunkQ;
        int rowsM = q / BM;
        int nwg = (N / BN) * rowsM;
        dist_mfma_kernel<<<dim3(nwg), dim3(256), 0, stream>>>(Asp, Bsp, x2, y2, keybuf, q0, N, rowsM);
        select4_kernel<<<dim3(q), dim3(SEL_T), 0, stream>>>(keybuf, L, Q, Dta, out, q0, N, n, out_size);
    }
}

// Round 6
// 588.085 us; speedup vs baseline: 1.5175x; 1.4946x over previous
//
#include <hip/hip_runtime.h>
#include <stdint.h>

#define D_FEAT 128
#define TOPK   128
#define KSPLIT 384            // 3 x 128 (h|h|l) . (h|l|h)
#define SCALE  4096.0f
#define SCALE2 16777216.0f    // SCALE^2 (2^24, exact)

typedef float    f32x4 __attribute__((ext_vector_type(4)));
typedef _Float16 half8 __attribute__((ext_vector_type(8)));

// ---------------- squared norms (unscaled f32) ----------------
__global__ __launch_bounds__(256) void sqnorm_kernel(const float* __restrict__ X,
                                                     float* __restrict__ out, int rows) {
    int r = blockIdx.x * 256 + threadIdx.x;
    if (r >= rows) return;
    const float4* p = (const float4*)(X + (size_t)r * D_FEAT);
    float s = 0.f;
    #pragma unroll
    for (int i = 0; i < D_FEAT / 4; ++i) {
        float4 v = p[i];
        s += v.x * v.x + v.y * v.y + v.z * v.z + v.w * v.w;
    }
    out[r] = s;
}

// ---------------- f32 -> scaled f16 (hi,lo) split, K-concatenated ----------------
__global__ __launch_bounds__(128) void split_kernel(const float* __restrict__ X,
                                                    unsigned short* __restrict__ out,
                                                    int isA) {
    int row = blockIdx.x;
    int k   = threadIdx.x;
    float a = X[(size_t)row * D_FEAT + k] * SCALE;
    _Float16 h = (_Float16)a;
    float hf = (float)h;
    _Float16 l = (_Float16)(a - hf);
    unsigned short hu, lu;
    __builtin_memcpy(&hu, &h, 2);
    __builtin_memcpy(&lu, &l, 2);
    size_t b = (size_t)row * KSPLIT;
    out[b + k]              = hu;
    out[b + D_FEAT + k]     = isA ? hu : lu;
    out[b + 2 * D_FEAT + k] = isA ? lu : hu;
}

// ---------------- MFMA distance kernel (gload_lds + dbuf) -> 16-bit keys ----------------
#define BM 128
#define BN 256
#define BKS 32                 // 32 halves = 64 B = one full line per row per slab
#define NSLAB (KSPLIT / BKS)   // 12
#define ASLOT (BM * 4)         // 512 16B-slots
#define BSLOT (BN * 4)         // 1024 16B-slots
#define BUFELEM ((ASLOT + BSLOT) * 8)   // u16 elems per buffer (12288 = 24 KB)

static __device__ __forceinline__ half8 lds_read_half8(const unsigned short* p) {
    half8 r;
    __builtin_memcpy(&r, p, 16);
    return r;
}

static __device__ __forceinline__ void gload_lds16(const unsigned short* g, unsigned short* l) {
    __builtin_amdgcn_global_load_lds(
        (const __attribute__((address_space(1))) unsigned int*)g,
        (__attribute__((address_space(3))) unsigned int*)l, 16, 0, 0);
}

// stage one BK=32 slab of A(128 rows) + B(256 rows) into buf via global_load_lds.
// LDS is linear in slot = row*4 + c ; the GLOBAL chunk is pre-swizzled sc = c ^ ((row>>1)&3)
// so that compute-side ds_read_b128 (which applies the same XOR) is conflict-free.
static __device__ __forceinline__ void stage_slab(
        const unsigned short* __restrict__ Asp,
        const unsigned short* __restrict__ Bsp,
        unsigned short* buf, int aRowBase, int bRowBase, int kt, int w, int l) {
    {   // A: 512 slots, one wave-round
        int slot = w * 64 + l;
        int row = slot >> 2, c = slot & 3;
        int sc  = c ^ ((row >> 1) & 3);
        gload_lds16(Asp + (size_t)(aRowBase + row) * KSPLIT + kt + sc * 8,
                    buf + (size_t)(w * 64) * 8);
    }
    #pragma unroll
    for (int r = 0; r < 2; ++r) {   // B: 1024 slots, two wave-rounds
        int slot = r * 512 + w * 64 + l;
        int row = slot >> 2, c = slot & 3;
        int sc  = c ^ ((row >> 1) & 3);
        gload_lds16(Bsp + (size_t)(bRowBase + row) * KSPLIT + kt + sc * 8,
                    buf + ASLOT * 8 + (size_t)(r * 512 + w * 64) * 8);
    }
}

__global__ __launch_bounds__(512, 4) void dist_mfma_kernel(
        const unsigned short* __restrict__ Asp,   // [n][384]
        const unsigned short* __restrict__ Bsp,   // [N][384]
        const float* __restrict__ x2,
        const float* __restrict__ y2,
        unsigned short* __restrict__ keyout,      // row-major [chunk][N]
        int q0, int N, int rowsM) {
    __shared__ __align__(16) unsigned short sh[2 * BUFELEM];   // 48 KB
    unsigned short* bufA = sh;
    unsigned short* bufB = sh + BUFELEM;

    // XCD-aware swizzle: column-major per XCD (contiguous N-band per XCD)
    const int nwg = (N / BN) * rowsM;      // multiple of 8
    const int cpx = nwg >> 3;
    const int bid = blockIdx.x;
    const int swz = (bid & 7) * cpx + (bid >> 3);
    const int col   = swz / rowsM;
    const int mrowi = swz - col * rowsM;
    const int nb = col * BN;
    const int mb = mrowi * BM;

    const int tid  = threadIdx.x;
    const int lane = tid & 63;
    const int w    = tid >> 6;
    const int wr   = w >> 2, wc = w & 3;   // 2 x 4 wave grid, 64x64 per wave

    f32x4 acc[4][4];
    #pragma unroll
    for (int i = 0; i < 4; ++i)
        #pragma unroll
        for (int j = 0; j < 4; ++j)
            acc[i][j] = (f32x4){0.f, 0.f, 0.f, 0.f};

    stage_slab(Asp, Bsp, bufA, q0 + mb, nb, 0, w, lane);

    const int c = lane >> 4;               // K chunk 0..3
    for (int s = 0; s < NSLAB; ++s) {
        __syncthreads();                   // drains stage(s) [vmcnt0] + compute(s-1) done
        unsigned short* cur = (s & 1) ? bufB : bufA;
        unsigned short* nxt = (s & 1) ? bufA : bufB;
        if (s + 1 < NSLAB)
            stage_slab(Asp, Bsp, nxt, q0 + mb, nb, (s + 1) * BKS, w, lane);  // DMA overlaps MFMA
        const unsigned short* Acur = cur;
        const unsigned short* Bcur = cur + ASLOT * 8;
        half8 af[4], bf[4];
        #pragma unroll
        for (int f = 0; f < 4; ++f) {
            int m  = wr * 64 + f * 16 + (lane & 15);
            af[f] = lds_read_half8(Acur + (size_t)(m * 4 + (c ^ ((m >> 1) & 3))) * 8);
            int nn = wc * 64 + f * 16 + (lane & 15);
            bf[f] = lds_read_half8(Bcur + (size_t)(nn * 4 + (c ^ ((nn >> 1) & 3))) * 8);
        }
        #pragma unroll
        for (int i = 0; i < 4; ++i)
            #pragma unroll
            for (int j = 0; j < 4; ++j)
                acc[i][j] = __builtin_amdgcn_mfma_f32_16x16x32_f16(af[i], bf[j], acc[i][j], 0, 0, 0);
    }

    // ---- epilogue: direct key16 stores (row-major) ----
    float x2v[16];
    #pragma unroll
    for (int fi = 0; fi < 4; ++fi)
        #pragma unroll
        for (int r = 0; r < 4; ++r)
            x2v[fi * 4 + r] = x2[q0 + mb + wr * 64 + fi * 16 + (lane >> 4) * 4 + r];
    #pragma unroll
    for (int fj = 0; fj < 4; ++fj) {
        float yv = y2[nb + wc * 64 + fj * 16 + (lane & 15)];
        #pragma unroll
        for (int fi = 0; fi < 4; ++fi) {
            #pragma unroll
            for (int r = 0; r < 4; ++r) {
                float d = fmaf(-2.0f, acc[fi][fj][r], SCALE2 * (x2v[fi * 4 + r] + yv));
                d = fmaxf(d, 0.0f);
                int m  = mb + wr * 64 + fi * 16 + (lane >> 4) * 4 + r;
                int nn = nb + wc * 64 + fj * 16 + (lane & 15);
                keyout[(size_t)m * N + nn] = (unsigned short)(__float_as_uint(d) >> 15);
            }
        }
    }
}

// ---------------- selection + vote on 16-bit keys (row-major) ----------------
#define SEL_T 1024
#define NPK   32
#define CAP   2048

__global__ __launch_bounds__(SEL_T, 4) void select4_kernel(
        const unsigned short* __restrict__ keys,
        const float* __restrict__ labels,
        const float* __restrict__ Q, const float* __restrict__ Dta,
        int* __restrict__ out, int q0, int N, int n_total, int out_size) {
    const int tid = threadIdx.x;
    const int qi  = q0 + blockIdx.x;
    const unsigned short* row = keys + (size_t)blockIdx.x * N;

    uint32_t pk[NPK];
    #pragma unroll
    for (int i = 0; i < 8; ++i) {
        uint4 v = *(const uint4*)(row + i * 8192 + tid * 8);
        pk[i * 4 + 0] = v.x; pk[i * 4 + 1] = v.y;
        pk[i * 4 + 2] = v.z; pk[i * 4 + 3] = v.w;
    }
    // pk[r] halves cover j = (r>>2)*8192 + tid*8 + (r&3)*2 + h

    __shared__ unsigned int red[2][3][16];
    __shared__ unsigned int tot[2][3];
    __shared__ unsigned int mcnt, votes_sh;
    __shared__ double       cval[CAP];
    __shared__ unsigned int ckey[CAP];

    if (tid == 0) { mcnt = 0; votes_sh = 0; }

    // 8 passes x 3 probes: resolve 16-bit tau (smallest t with count(key<t) >= TOPK)
    uint32_t lo = 0, hi = 65536, base = 0;
    #pragma unroll
    for (int pass = 0; pass < 8; ++pass) {
        uint32_t qs = (hi - lo) >> 2;
        uint32_t p1 = lo + qs, p2 = p1 + qs, p3 = p2 + qs;
        uint32_t c1 = 0, c2 = 0, c3 = 0;
        #pragma unroll
        for (int r2 = 0; r2 < NPK; ++r2) {
            uint32_t p = pk[r2];
            uint32_t a = p & 0xFFFFu, b = p >> 16;
            c1 += (a < p1) + (b < p1);
            c2 += (a < p2) + (b < p2);
            c3 += (a < p3) + (b < p3);
        }
        #pragma unroll
        for (int off = 32; off > 0; off >>= 1) {
            c1 += __shfl_down(c1, off, 64);
            c2 += __shfl_down(c2, off, 64);
            c3 += __shfl_down(c3, off, 64);
        }
        int bsel = pass & 1;
        if ((tid & 63) == 0) {
            int ww = tid >> 6;
            red[bsel][0][ww] = c1; red[bsel][1][ww] = c2; red[bsel][2][ww] = c3;
        }
        __syncthreads();
        if (tid < 48) {
            int g = tid >> 4, i = tid & 15;
            unsigned int v = red[bsel][g][i];
            v += __shfl_xor(v, 1, 64);
            v += __shfl_xor(v, 2, 64);
            v += __shfl_xor(v, 4, 64);
            v += __shfl_xor(v, 8, 64);
            if (i == 0) tot[bsel][g] = v;
        }
        __syncthreads();
        uint32_t t1 = tot[bsel][0], t2 = tot[bsel][1], t3 = tot[bsel][2];
        if      (t1 >= TOPK) { hi = p1; }
        else if (t2 >= TOPK) { lo = p1; hi = p2; base = t1; }
        else if (t3 >= TOPK) { lo = p2; hi = p3; base = t2; }
        else                 { lo = p3;          base = t3; }
    }
    const uint32_t tau    = lo;
    const uint32_t t_take = TOPK - base;

    // ---- vote below tau; gather tau-ties with exact f64 distances ----
    uint32_t votes = 0;
    #pragma unroll
    for (int r2 = 0; r2 < NPK; ++r2) {
        uint32_t p = pk[r2];
        #pragma unroll
        for (int h = 0; h < 2; ++h) {
            uint32_t key = (h == 0) ? (p & 0xFFFFu) : (p >> 16);
            if (key <= tau) {
                int j = (r2 >> 2) * 8192 + tid * 8 + (r2 & 3) * 2 + h;
                if (key < tau) {
                    votes += (labels[j] > 0.5f) ? 1u : 0u;
                } else {
                    unsigned int lab = (labels[j] > 0.5f) ? 0x80000000u : 0u;
                    unsigned int e = atomicAdd(&mcnt, 1u);
                    if (e < CAP) {
                        const float* qp = Q   + (size_t)qi * D_FEAT;
                        const float* dp = Dta + (size_t)j  * D_FEAT;
                        double sacc = 0.0;
                        for (int k = 0; k < D_FEAT; ++k) {
                            double df = (double)qp[k] - (double)dp[k];
                            sacc = fma(df, df, sacc);
                        }
                        cval[e] = sacc;
                        ckey[e] = (unsigned int)j | lab;
                    }
                }
            }
        }
    }
    #pragma unroll
    for (int off = 32; off > 0; off >>= 1)
        votes += __shfl_down(votes, off, 64);
    if ((tid & 63) == 0 && votes) atomicAdd(&votes_sh, votes);
    __syncthreads();

    unsigned int m = mcnt; if (m > CAP) m = CAP;
    for (unsigned int e = tid; e < m; e += SEL_T) {
        double       ve = cval[e];
        unsigned int ke = ckey[e];
        unsigned int ie = ke & 0x7FFFFFFFu;
        unsigned int rank = 0;
        for (unsigned int f = 0; f < m; ++f) {
            double       vf = cval[f];
            unsigned int jf = ckey[f] & 0x7FFFFFFFu;
            rank += (vf < ve || (vf == ve && jf < ie)) ? 1u : 0u;
        }
        if (rank < t_take && (ke & 0x80000000u)) atomicAdd(&votes_sh, 1u);
    }
    __syncthreads();

    if (tid == 0) {
        unsigned int v1 = votes_sh;
        out[qi] = (v1 > TOPK / 2) ? 1 : 0;          // 64/64 tie -> class 0
        if (qi == 0 && out_size > n_total) out[n_total] = 0;
    }
}

// ---------------- host ----------------
extern "C" void kernel_launch(void* const* d_in, const int* in_sizes, int n_in,
                              void* d_out, int out_size, void* d_ws, size_t ws_size,
                              hipStream_t stream) {
    const float* Q   = (const float*)d_in[0];
    const float* Dta = (const float*)d_in[1];
    const float* L   = (const float*)d_in[2];
    const int n = in_sizes[0] / D_FEAT;    // 2048
    const int N = in_sizes[1] / D_FEAT;    // 65536
    int* out = (int*)d_out;

    char* ws = (char*)d_ws;
    size_t off = 0;
    float* y2 = (float*)(ws + off); off += (((size_t)N * 4) + 255) & ~(size_t)255;
    float* x2 = (float*)(ws + off); off += (((size_t)n * 4) + 255) & ~(size_t)255;
    unsigned short* Asp = (unsigned short*)(ws + off); off += (((size_t)n * KSPLIT * 2) + 255) & ~(size_t)255;
    unsigned short* Bsp = (unsigned short*)(ws + off); off += (((size_t)N * KSPLIT * 2) + 255) & ~(size_t)255;
    unsigned short* keybuf = (unsigned short*)(ws + off);
    size_t avail = (ws_size > off) ? (ws_size - off) : 0;

    long maxQ = (long)(avail / ((size_t)N * 2));
    int chunkQ;
    if (maxQ >= n) chunkQ = n;
    else { chunkQ = (int)((maxQ / BM) * BM); if (chunkQ < BM) chunkQ = BM; }

    sqnorm_kernel<<<dim3((N + 255) / 256), dim3(256), 0, stream>>>(Dta, y2, N);
    sqnorm_kernel<<<dim3((n + 255) / 256), dim3(256), 0, stream>>>(Q, x2, n);
    split_kernel<<<dim3(n), dim3(128), 0, stream>>>(Q, Asp, 1);
    split_kernel<<<dim3(N), dim3(128), 0, stream>>>(Dta, Bsp, 0);

    for (int q0 = 0; q0 < n; q0 += chunkQ) {
        int q = n - q0; if (q > chunkQ) q = chunkQ;
        int rowsM = q / BM;
        int nwg = (N / BN) * rowsM;
        dist_mfma_kernel<<<dim3(nwg), dim3(512), 0, stream>>>(Asp, Bsp, x2, y2, keybuf, q0, N, rowsM);
        select4_kernel<<<dim3(q), dim3(SEL_T), 0, stream>>>(keybuf, L, Q, Dta, out, q0, N, n, out_size);
    }
}

// Round 7
// 488.820 us; speedup vs baseline: 1.8257x; 1.2031x over previous
//
#include <hip/hip_runtime.h>
#include <stdint.h>

#define D_FEAT 128
#define TOPK   128
#define KSPLIT 384            // 3 x 128 (h|h|l) . (h|l|h)
#define SCALE  4096.0f
#define SCALE2 16777216.0f    // SCALE^2 (2^24, exact)

typedef float    f32x4 __attribute__((ext_vector_type(4)));
typedef _Float16 half8 __attribute__((ext_vector_type(8)));

// ---------------- squared norms (unscaled f32) ----------------
__global__ __launch_bounds__(256) void sqnorm_kernel(const float* __restrict__ X,
                                                     float* __restrict__ out, int rows) {
    int r = blockIdx.x * 256 + threadIdx.x;
    if (r >= rows) return;
    const float4* p = (const float4*)(X + (size_t)r * D_FEAT);
    float s = 0.f;
    #pragma unroll
    for (int i = 0; i < D_FEAT / 4; ++i) {
        float4 v = p[i];
        s += v.x * v.x + v.y * v.y + v.z * v.z + v.w * v.w;
    }
    out[r] = s;
}

// ---------------- f32 -> scaled f16 (hi,lo) split, K-concatenated ----------------
__global__ __launch_bounds__(128) void split_kernel(const float* __restrict__ X,
                                                    unsigned short* __restrict__ out,
                                                    int isA) {
    int row = blockIdx.x;
    int k   = threadIdx.x;
    float a = X[(size_t)row * D_FEAT + k] * SCALE;
    _Float16 h = (_Float16)a;
    float hf = (float)h;
    _Float16 l = (_Float16)(a - hf);
    unsigned short hu, lu;
    __builtin_memcpy(&hu, &h, 2);
    __builtin_memcpy(&lu, &l, 2);
    size_t b = (size_t)row * KSPLIT;
    out[b + k]              = hu;
    out[b + D_FEAT + k]     = isA ? hu : lu;
    out[b + 2 * D_FEAT + k] = isA ? lu : hu;
}

// ---------------- MFMA distance kernel (gload_lds + dbuf) -> 16-bit keys ----------------
#define BM 128
#define BN 256
#define BKS 32                 // 32 halves = 64 B per row per slab
#define NSLAB (KSPLIT / BKS)   // 12
#define ASLOT (BM * 4)         // 512 16B-slots
#define BSLOT (BN * 4)         // 1024 16B-slots
#define BUFELEM ((ASLOT + BSLOT) * 8)   // u16 elems per buffer (12288 = 24 KB)

static __device__ __forceinline__ half8 lds_read_half8(const unsigned short* p) {
    half8 r;
    __builtin_memcpy(&r, p, 16);
    return r;
}

static __device__ __forceinline__ void gload_lds16(const unsigned short* g, unsigned short* l) {
    __builtin_amdgcn_global_load_lds(
        (const __attribute__((address_space(1))) unsigned int*)g,
        (__attribute__((address_space(3))) unsigned int*)l, 16, 0, 0);
}

// stage one BK=32 slab of A(128 rows) + B(256 rows) into buf via global_load_lds.
// LDS dest is linear in slot = row*4 + c ; GLOBAL source chunk is pre-swizzled
// sc = c ^ ((row>>1)&3) so compute-side ds_read_b128 (same XOR) is conflict-free.
static __device__ __forceinline__ void stage_slab(
        const unsigned short* __restrict__ Asp,
        const unsigned short* __restrict__ Bsp,
        unsigned short* buf, int aRowBase, int bRowBase, int kt, int w, int l) {
    {   // A: 512 slots, one wave-round
        int slot = w * 64 + l;
        int row = slot >> 2, c = slot & 3;
        int sc  = c ^ ((row >> 1) & 3);
        gload_lds16(Asp + (size_t)(aRowBase + row) * KSPLIT + kt + sc * 8,
                    buf + (size_t)(w * 64) * 8);
    }
    #pragma unroll
    for (int r = 0; r < 2; ++r) {   // B: 1024 slots, two wave-rounds
        int slot = r * 512 + w * 64 + l;
        int row = slot >> 2, c = slot & 3;
        int sc  = c ^ ((row >> 1) & 3);
        gload_lds16(Bsp + (size_t)(bRowBase + row) * KSPLIT + kt + sc * 8,
                    buf + ASLOT * 8 + (size_t)(r * 512 + w * 64) * 8);
    }
}

__global__ __launch_bounds__(512, 4) void dist_mfma_kernel(
        const unsigned short* __restrict__ Asp,   // [n][384]
        const unsigned short* __restrict__ Bsp,   // [N][384]
        const float* __restrict__ x2,
        const float* __restrict__ y2,
        unsigned short* __restrict__ keyout,      // row-major [chunk][N]
        int q0, int N, int rowsM) {
    __shared__ __align__(16) unsigned short sh[2 * BUFELEM];   // 48 KB
    unsigned short* bufA = sh;
    unsigned short* bufB = sh + BUFELEM;

    // XCD-aware swizzle: column-major per XCD (contiguous N-band per XCD)
    const int nwg = (N / BN) * rowsM;      // multiple of 8
    const int cpx = nwg >> 3;
    const int bid = blockIdx.x;
    const int swz = (bid & 7) * cpx + (bid >> 3);
    const int col   = swz / rowsM;
    const int mrowi = swz - col * rowsM;
    const int nb = col * BN;
    const int mb = mrowi * BM;

    const int tid  = threadIdx.x;
    const int lane = tid & 63;
    const int w    = tid >> 6;
    const int wr   = w >> 2, wc = w & 3;   // 2 x 4 wave grid, 64x64 per wave

    f32x4 acc[4][4];
    #pragma unroll
    for (int i = 0; i < 4; ++i)
        #pragma unroll
        for (int j = 0; j < 4; ++j)
            acc[i][j] = (f32x4){0.f, 0.f, 0.f, 0.f};

    stage_slab(Asp, Bsp, bufA, q0 + mb, nb, 0, w, lane);

    const int c = lane >> 4;               // K chunk 0..3
    for (int s = 0; s < NSLAB; ++s) {
        __syncthreads();                   // drains stage(s) [vmcnt0] + compute(s-1) done
        unsigned short* cur = (s & 1) ? bufB : bufA;
        unsigned short* nxt = (s & 1) ? bufA : bufB;
        if (s + 1 < NSLAB)
            stage_slab(Asp, Bsp, nxt, q0 + mb, nb, (s + 1) * BKS, w, lane);  // DMA overlaps MFMA
        const unsigned short* Acur = cur;
        const unsigned short* Bcur = cur + ASLOT * 8;
        half8 af[4], bf[4];
        #pragma unroll
        for (int f = 0; f < 4; ++f) {
            int m  = wr * 64 + f * 16 + (lane & 15);
            af[f] = lds_read_half8(Acur + (size_t)(m * 4 + (c ^ ((m >> 1) & 3))) * 8);
            int nn = wc * 64 + f * 16 + (lane & 15);
            bf[f] = lds_read_half8(Bcur + (size_t)(nn * 4 + (c ^ ((nn >> 1) & 3))) * 8);
        }
        #pragma unroll
        for (int i = 0; i < 4; ++i)
            #pragma unroll
            for (int j = 0; j < 4; ++j)
                acc[i][j] = __builtin_amdgcn_mfma_f32_16x16x32_f16(af[i], bf[j], acc[i][j], 0, 0, 0);
    }

    // ---- epilogue: direct key16 stores (row-major) ----
    float x2v[16];
    #pragma unroll
    for (int fi = 0; fi < 4; ++fi)
        #pragma unroll
        for (int r = 0; r < 4; ++r)
            x2v[fi * 4 + r] = x2[q0 + mb + wr * 64 + fi * 16 + (lane >> 4) * 4 + r];
    #pragma unroll
    for (int fj = 0; fj < 4; ++fj) {
        float yv = y2[nb + wc * 64 + fj * 16 + (lane & 15)];
        #pragma unroll
        for (int fi = 0; fi < 4; ++fi) {
            #pragma unroll
            for (int r = 0; r < 4; ++r) {
                float d = fmaf(-2.0f, acc[fi][fj][r], SCALE2 * (x2v[fi * 4 + r] + yv));
                d = fmaxf(d, 0.0f);
                int m  = mb + wr * 64 + fi * 16 + (lane >> 4) * 4 + r;
                int nn = nb + wc * 64 + fj * 16 + (lane & 15);
                keyout[(size_t)m * N + nn] = (unsigned short)(__float_as_uint(d) >> 15);
            }
        }
    }
}

// ---------------- selection + vote on 16-bit keys (row-major) ----------------
#define SEL_T 1024
#define NPK   32
#define CAP   2048

__global__ __launch_bounds__(SEL_T, 8) void select4_kernel(
        const unsigned short* __restrict__ keys,
        const float* __restrict__ labels,
        const float* __restrict__ Q, const float* __restrict__ Dta,
        int* __restrict__ out, int q0, int N, int n_total, int out_size) {
    const int tid = threadIdx.x;
    const int qi  = q0 + blockIdx.x;
    const unsigned short* row = keys + (size_t)blockIdx.x * N;

    uint32_t pk[NPK];
    #pragma unroll
    for (int i = 0; i < 8; ++i) {
        uint4 v = *(const uint4*)(row + i * 8192 + tid * 8);
        pk[i * 4 + 0] = v.x; pk[i * 4 + 1] = v.y;
        pk[i * 4 + 2] = v.z; pk[i * 4 + 3] = v.w;
    }
    // Pin keys into VGPRs: block rematerialization (compiler otherwise re-reads
    // the row from memory on EVERY search pass — 8x traffic, VGPR_Count=40 tell).
    #pragma unroll
    for (int r2 = 0; r2 < NPK; ++r2) asm volatile("" : "+v"(pk[r2]));
    // pk[r] halves cover j = (r>>2)*8192 + tid*8 + (r&3)*2 + h

    __shared__ unsigned int red[2][3][16];
    __shared__ unsigned int tot[2][3];
    __shared__ unsigned int mcnt, votes_sh;
    __shared__ double       cval[CAP];
    __shared__ unsigned int ckey[CAP];

    if (tid == 0) { mcnt = 0; votes_sh = 0; }

    // 8 passes x 3 probes: resolve 16-bit tau (smallest t with count(key<t) >= TOPK)
    uint32_t lo = 0, hi = 65536, base = 0;
    #pragma unroll
    for (int pass = 0; pass < 8; ++pass) {
        uint32_t qs = (hi - lo) >> 2;
        uint32_t p1 = lo + qs, p2 = p1 + qs, p3 = p2 + qs;
        uint32_t c1 = 0, c2 = 0, c3 = 0;
        #pragma unroll
        for (int r2 = 0; r2 < NPK; ++r2) {
            uint32_t p = pk[r2];
            uint32_t a = p & 0xFFFFu, b = p >> 16;
            c1 += (a < p1) + (b < p1);
            c2 += (a < p2) + (b < p2);
            c3 += (a < p3) + (b < p3);
        }
        #pragma unroll
        for (int off = 32; off > 0; off >>= 1) {
            c1 += __shfl_down(c1, off, 64);
            c2 += __shfl_down(c2, off, 64);
            c3 += __shfl_down(c3, off, 64);
        }
        int bsel = pass & 1;
        if ((tid & 63) == 0) {
            int ww = tid >> 6;
            red[bsel][0][ww] = c1; red[bsel][1][ww] = c2; red[bsel][2][ww] = c3;
        }
        __syncthreads();
        if (tid < 48) {
            int g = tid >> 4, i = tid & 15;
            unsigned int v = red[bsel][g][i];
            v += __shfl_xor(v, 1, 64);
            v += __shfl_xor(v, 2, 64);
            v += __shfl_xor(v, 4, 64);
            v += __shfl_xor(v, 8, 64);
            if (i == 0) tot[bsel][g] = v;
        }
        __syncthreads();
        uint32_t t1 = tot[bsel][0], t2 = tot[bsel][1], t3 = tot[bsel][2];
        if      (t1 >= TOPK) { hi = p1; }
        else if (t2 >= TOPK) { lo = p1; hi = p2; base = t1; }
        else if (t3 >= TOPK) { lo = p2; hi = p3; base = t2; }
        else                 { lo = p3;          base = t3; }
    }
    const uint32_t tau    = lo;
    const uint32_t t_take = TOPK - base;

    // ---- vote below tau; gather tau-ties with exact f64 distances ----
    uint32_t votes = 0;
    #pragma unroll
    for (int r2 = 0; r2 < NPK; ++r2) {
        uint32_t p = pk[r2];
        #pragma unroll
        for (int h = 0; h < 2; ++h) {
            uint32_t key = (h == 0) ? (p & 0xFFFFu) : (p >> 16);
            if (key <= tau) {
                int j = (r2 >> 2) * 8192 + tid * 8 + (r2 & 3) * 2 + h;
                if (key < tau) {
                    votes += (labels[j] > 0.5f) ? 1u : 0u;
                } else {
                    unsigned int lab = (labels[j] > 0.5f) ? 0x80000000u : 0u;
                    unsigned int e = atomicAdd(&mcnt, 1u);
                    if (e < CAP) {
                        const float* qp = Q   + (size_t)qi * D_FEAT;
                        const float* dp = Dta + (size_t)j  * D_FEAT;
                        double sacc = 0.0;
                        for (int k = 0; k < D_FEAT; ++k) {
                            double df = (double)qp[k] - (double)dp[k];
                            sacc = fma(df, df, sacc);
                        }
                        cval[e] = sacc;
                        ckey[e] = (unsigned int)j | lab;
                    }
                }
            }
        }
    }
    #pragma unroll
    for (int off = 32; off > 0; off >>= 1)
        votes += __shfl_down(votes, off, 64);
    if ((tid & 63) == 0 && votes) atomicAdd(&votes_sh, votes);
    __syncthreads();

    unsigned int m = mcnt; if (m > CAP) m = CAP;
    for (unsigned int e = tid; e < m; e += SEL_T) {
        double       ve = cval[e];
        unsigned int ke = ckey[e];
        unsigned int ie = ke & 0x7FFFFFFFu;
        unsigned int rank = 0;
        for (unsigned int f = 0; f < m; ++f) {
            double       vf = cval[f];
            unsigned int jf = ckey[f] & 0x7FFFFFFFu;
            rank += (vf < ve || (vf == ve && jf < ie)) ? 1u : 0u;
        }
        if (rank < t_take && (ke & 0x80000000u)) atomicAdd(&votes_sh, 1u);
    }
    __syncthreads();

    if (tid == 0) {
        unsigned int v1 = votes_sh;
        out[qi] = (v1 > TOPK / 2) ? 1 : 0;          // 64/64 tie -> class 0
        if (qi == 0 && out_size > n_total) out[n_total] = 0;
    }
}

// ---------------- host ----------------
extern "C" void kernel_launch(void* const* d_in, const int* in_sizes, int n_in,
                              void* d_out, int out_size, void* d_ws, size_t ws_size,
                              hipStream_t stream) {
    const float* Q   = (const float*)d_in[0];
    const float* Dta = (const float*)d_in[1];
    const float* L   = (const float*)d_in[2];
    const int n = in_sizes[0] / D_FEAT;    // 2048
    const int N = in_sizes[1] / D_FEAT;    // 65536
    int* out = (int*)d_out;

    char* ws = (char*)d_ws;
    size_t off = 0;
    float* y2 = (float*)(ws + off); off += (((size_t)N * 4) + 255) & ~(size_t)255;
    float* x2 = (float*)(ws + off); off += (((size_t)n * 4) + 255) & ~(size_t)255;
    unsigned short* Asp = (unsigned short*)(ws + off); off += (((size_t)n * KSPLIT * 2) + 255) & ~(size_t)255;
    unsigned short* Bsp = (unsigned short*)(ws + off); off += (((size_t)N * KSPLIT * 2) + 255) & ~(size_t)255;
    unsigned short* keybuf = (unsigned short*)(ws + off);
    size_t avail = (ws_size > off) ? (ws_size - off) : 0;

    long maxQ = (long)(avail / ((size_t)N * 2));
    int chunkQ;
    if (maxQ >= n) chunkQ = n;
    else { chunkQ = (int)((maxQ / BM) * BM); if (chunkQ < BM) chunkQ = BM; }

    sqnorm_kernel<<<dim3((N + 255) / 256), dim3(256), 0, stream>>>(Dta, y2, N);
    sqnorm_kernel<<<dim3((n + 255) / 256), dim3(256), 0, stream>>>(Q, x2, n);
    split_kernel<<<dim3(n), dim3(128), 0, stream>>>(Q, Asp, 1);
    split_kernel<<<dim3(N), dim3(128), 0, stream>>>(Dta, Bsp, 0);

    for (int q0 = 0; q0 < n; q0 += chunkQ) {
        int q = n - q0; if (q > chunkQ) q = chunkQ;
        int rowsM = q / BM;
        int nwg = (N / BN) * rowsM;
        dist_mfma_kernel<<<dim3(nwg), dim3(512), 0, stream>>>(Asp, Bsp, x2, y2, keybuf, q0, N, rowsM);
        select4_kernel<<<dim3(q), dim3(SEL_T), 0, stream>>>(keybuf, L, Q, Dta, out, q0, N, n, out_size);
    }
}